// Round 1
// baseline (36.441 us; speedup 1.0000x reference)
//
#include <hip/hip_runtime.h>

#define B_  4
#define QL  128
#define CL  512
#define XD  64
#define ED  128
#define DD  128
#define YD  32

typedef __attribute__((ext_vector_type(8))) short bf16x8;
typedef __attribute__((ext_vector_type(4))) float f32x4;

__device__ __forceinline__ unsigned short f2bf(float x) {
  union { float f; unsigned int u; } v; v.f = x;
  unsigned int u = v.u;
  return (unsigned short)((u + 0x7FFFu + ((u >> 16) & 1u)) >> 16);  // RNE
}

// fp[b][c][d] = sum_e f[b][c][e] * W0[XD+e][d]   (b0 is baked into qp, not here)
__global__ void fp_kernel(const float* __restrict__ f, const float* __restrict__ W0,
                          float* __restrict__ fp) {
  int row = blockIdx.x;            // b*CL + c
  int d = threadIdx.x;             // 0..127
  __shared__ float fr[ED];
  fr[d] = f[(size_t)row * ED + d];
  __syncthreads();
  float acc = 0.f;
  const float* w = W0 + XD * DD + d;
  #pragma unroll
  for (int e = 0; e < ED; ++e) acc = fmaf(fr[e], w[e * DD], acc);
  fp[(size_t)row * DD + d] = acc;
}

// W1 transposed to [j][d] bf16, PRE-SWIZZLED: ushort index j*128 + (d ^ ((j&7)<<3))
// so a linear LDS copy lands in the bank-conflict-free layout.
__global__ void w1t_kernel(const float* __restrict__ W1, unsigned short* __restrict__ w1t) {
  int e = blockIdx.x * 256 + threadIdx.x;   // 0..16383
  int j = e & 127;                          // coalesced read along j
  int d = e >> 7;
  w1t[j * 128 + (d ^ ((j & 7) << 3))] = f2bf(W1[d * DD + j]);
}

__launch_bounds__(256, 2)
__global__ void main_kernel(const float* __restrict__ q,
                            const float* __restrict__ logits,
                            const float* __restrict__ fp,
                            const unsigned short* __restrict__ w1t,
                            const float* __restrict__ W0,
                            const float* __restrict__ b0,
                            const float* __restrict__ b1,
                            const float* __restrict__ Wo,
                            const float* __restrict__ bo,
                            float* __restrict__ out) {
  __shared__ __align__(16) unsigned short h1[128 * 128];  // 32KB, swizzled bf16 H1 tile
  __shared__ __align__(16) unsigned short w1[128 * 128];  // 32KB, swizzled bf16 W1^T
  __shared__ float att[CL];
  __shared__ float qp[DD];
  __shared__ float qrow[XD];
  __shared__ float g[4][DD];
  __shared__ float red[8];
  __shared__ float part[8][YD];

  const int tid = threadIdx.x;
  const int bid = blockIdx.x;          // b*QL + qi
  const int wid = tid >> 6;
  const int ln  = tid & 63;

  // ---- stage pre-swizzled W1^T into LDS (linear copy) ----
  {
    const uint4* src = (const uint4*)w1t;
    uint4* dst = (uint4*)w1;
    #pragma unroll
    for (int i = 0; i < 8; ++i) dst[i * 256 + tid] = src[i * 256 + tid];
  }
  if (tid < XD) qrow[tid] = q[(size_t)bid * XD + tid];
  ((float*)g)[tid] = 0.f;
  ((float*)g)[tid + 256] = 0.f;
  __syncthreads();

  // ---- qp[d] = b0[d] + sum_x qrow[x]*W0[x][d] ----
  if (tid < DD) {
    float acc = b0[tid];
    const float* w = W0 + tid;
    #pragma unroll
    for (int x = 0; x < XD; ++x) acc = fmaf(qrow[x], w[x * DD], acc);
    qp[tid] = acc;
  }

  // ---- softmax over the 512 logits of this (b,q) row ----
  {
    const float* lg = logits + (size_t)bid * CL;
    float l0 = lg[tid], l1 = lg[tid + 256];
    float m = fmaxf(l0, l1);
    #pragma unroll
    for (int off = 1; off < 64; off <<= 1) m = fmaxf(m, __shfl_xor(m, off, 64));
    if (ln == 0) red[wid] = m;
    __syncthreads();
    m = fmaxf(fmaxf(red[0], red[1]), fmaxf(red[2], red[3]));
    float p0 = expf(l0 - m), p1 = expf(l1 - m);
    float s = p0 + p1;
    #pragma unroll
    for (int off = 1; off < 64; off <<= 1) s += __shfl_xor(s, off, 64);
    if (ln == 0) red[4 + wid] = s;
    __syncthreads();
    float inv = 1.f / (red[4] + red[5] + red[6] + red[7]);
    att[tid] = p0 * inv;
    att[tid + 256] = p1 * inv;
  }

  // wave tiling: 2x2 waves, each owns a 64c x 64j output tile
  const int wrow = wid >> 1;
  const int wcol = wid & 1;
  const int lhi = ln >> 4;
  const int llo = ln & 15;
  const int swz = (llo & 7) << 4;        // rows c0+16*ct and cols j0+16*jt keep (x&7)==llo&7
  const int c0 = wrow * 64 + llo;
  const int j0 = wcol * 64 + llo;
  const int b = bid >> 7;

  float b1v[4];
  #pragma unroll
  for (int jt = 0; jt < 4; ++jt) b1v[jt] = b1[j0 + jt * 16];

  float gp[4] = {0.f, 0.f, 0.f, 0.f};

  for (int citer = 0; citer < 4; ++citer) {
    // ---- build H1 tile: relu(qp + fp), bf16, XOR-swizzled ----
    const float* fpb = fp + ((size_t)(b * CL + citer * 128)) * DD;
    #pragma unroll 4
    for (int i = 0; i < 32; ++i) {
      int idx = i * 256 + tid;       // 0..8191 (float2 granules)
      int c = idx >> 6;              // 0..127
      int dp = idx & 63;             // float2 index within row
      float2 f2 = ((const float2*)(fpb + c * DD))[dp];
      float v0 = fmaxf(f2.x + qp[dp * 2], 0.f);
      float v1 = fmaxf(f2.y + qp[dp * 2 + 1], 0.f);
      unsigned int pk = (unsigned int)f2bf(v0) | ((unsigned int)f2bf(v1) << 16);
      ((unsigned int*)h1)[c * 64 + (dp ^ ((c & 7) << 2))] = pk;
    }
    __syncthreads();

    // ---- H2 tile = H1 @ W1 via mfma_f32_16x16x32_bf16 ----
    f32x4 zero = {0.f, 0.f, 0.f, 0.f};
    f32x4 acc[4][4];
    #pragma unroll
    for (int ct = 0; ct < 4; ++ct)
      #pragma unroll
      for (int jt = 0; jt < 4; ++jt) acc[ct][jt] = zero;

    #pragma unroll
    for (int kk = 0; kk < 4; ++kk) {
      const int kb = (kk * 64 + lhi * 16) ^ swz;
      bf16x8 a[4], bb[4];
      #pragma unroll
      for (int ct = 0; ct < 4; ++ct)
        a[ct] = *(const bf16x8*)((const char*)h1 + (c0 + ct * 16) * 256 + kb);
      #pragma unroll
      for (int jt = 0; jt < 4; ++jt)
        bb[jt] = *(const bf16x8*)((const char*)w1 + (j0 + jt * 16) * 256 + kb);
      #pragma unroll
      for (int ct = 0; ct < 4; ++ct)
        #pragma unroll
        for (int jt = 0; jt < 4; ++jt)
          acc[ct][jt] = __builtin_amdgcn_mfma_f32_16x16x32_bf16(a[ct], bb[jt], acc[ct][jt], 0, 0, 0);
    }

    // ---- epilogue: g[j] += att[c] * relu(H2 + b1)  (GEMM2 commuted away) ----
    const int cbase = citer * 128 + wrow * 64 + lhi * 4;
    #pragma unroll
    for (int ct = 0; ct < 4; ++ct) {
      #pragma unroll
      for (int r = 0; r < 4; ++r) {
        float wv = att[cbase + ct * 16 + r];
        #pragma unroll
        for (int jt = 0; jt < 4; ++jt) {
          float h = fmaxf(acc[ct][jt][r] + b1v[jt], 0.f);
          gp[jt] = fmaf(wv, h, gp[jt]);
        }
      }
    }
    __syncthreads();   // protect h1 before next tile overwrites it
  }

  // reduce gp across the 4 row-groups of each wave (rows differ, col j identical)
  #pragma unroll
  for (int jt = 0; jt < 4; ++jt) {
    gp[jt] += __shfl_xor(gp[jt], 16, 64);
    gp[jt] += __shfl_xor(gp[jt], 32, 64);
  }
  if (ln < 16) {
    #pragma unroll
    for (int jt = 0; jt < 4; ++jt) g[wid][j0 + jt * 16] = gp[jt];  // unwritten slots stay 0
  }
  __syncthreads();

  // ---- y = g @ Wo + bo (fp32, tiny) ----
  {
    int y = tid & 31, ch = tid >> 5;
    float a = 0.f;
    #pragma unroll
    for (int jj = 0; jj < 16; ++jj) {
      int j = ch * 16 + jj;
      float gj = g[0][j] + g[1][j] + g[2][j] + g[3][j];
      a = fmaf(gj, Wo[j * YD + y], a);
    }
    part[ch][y] = a;
  }
  __syncthreads();
  if (tid < YD) {
    float a = bo[tid];
    #pragma unroll
    for (int ch = 0; ch < 8; ++ch) a += part[ch][tid];
    out[(size_t)bid * YD + tid] = a;
  }
}

extern "C" void kernel_launch(void* const* d_in, const int* in_sizes, int n_in,
                              void* d_out, int out_size, void* d_ws, size_t ws_size,
                              hipStream_t stream) {
  const float* q  = (const float*)d_in[0];
  const float* f  = (const float*)d_in[1];
  const float* lg = (const float*)d_in[2];
  const float* W0 = (const float*)d_in[3];
  const float* b0 = (const float*)d_in[4];
  const float* W1 = (const float*)d_in[5];
  const float* b1 = (const float*)d_in[6];
  const float* Wo = (const float*)d_in[7];
  const float* bo = (const float*)d_in[8];
  float* out = (float*)d_out;

  // ws layout: fp f32 [4*512*128] (1MB) | w1t bf16 pre-swizzled [128*128] (32KB)
  float* fp = (float*)d_ws;
  unsigned short* w1t = (unsigned short*)((char*)d_ws + (size_t)B_ * CL * DD * 4);

  fp_kernel<<<B_ * CL, ED, 0, stream>>>(f, W0, fp);
  w1t_kernel<<<64, 256, 0, stream>>>(W1, w1t);
  main_kernel<<<B_ * QL, 256, 0, stream>>>(q, lg, fp, w1t, W0, b0, b1, Wo, bo, out);
}

// Round 2
// 26.353 us; speedup vs baseline: 1.3828x; 1.3828x over previous
//
#include <hip/hip_runtime.h>

#define B_  4
#define QL  128
#define CL  512
#define XD  64
#define ED  128
#define DD  128
#define YD  32

typedef __attribute__((ext_vector_type(8))) _Float16 f16x8;
typedef __attribute__((ext_vector_type(4))) float f32x4;

// ws layout (all 16B-aligned):
//   fph : f16 [B_*CL*DD]  = 512 KB   relu-input f-part, f16
//   qph : f16 [B_*QL*DD]  = 128 KB   q-part + b0, f16
//   w1f : f16 [16384]     =  32 KB   W1 fragment-ordered: [wcol][kk][jt][lane][e]
__global__ void prep_kernel(const float* __restrict__ q,
                            const float* __restrict__ f,
                            const float* __restrict__ W0,
                            const float* __restrict__ b0,
                            const float* __restrict__ W1,
                            _Float16* __restrict__ fph,
                            _Float16* __restrict__ qph,
                            _Float16* __restrict__ w1f) {
  const int bid = blockIdx.x, tid = threadIdx.x;
  __shared__ float sbuf[256];
  if (bid < 1024) {
    // fp rows: 2 rows per block. fp[row][d] = sum_e f[row][e]*W0[XD+e][d]
    const int sub = tid >> 7, d = tid & 127;
    const int row = bid * 2 + sub;
    sbuf[tid] = f[(size_t)row * ED + d];
    __syncthreads();
    float acc = 0.f;
    const float* w = W0 + XD * DD + d;
    const float* fr = sbuf + sub * 128;
    #pragma unroll 32
    for (int e = 0; e < ED; ++e) acc = fmaf(fr[e], w[e * DD], acc);
    fph[(size_t)row * DD + d] = (_Float16)acc;
  } else if (bid < 1280) {
    // qp rows: 2 rows per block. qp[row][d] = b0[d] + sum_x q[row][x]*W0[x][d]
    const int sub = tid >> 7, d = tid & 127;
    const int row = (bid - 1024) * 2 + sub;
    if (tid < 128) sbuf[tid] = q[((size_t)(bid - 1024) * 2 + (tid >> 6)) * XD + (tid & 63)];
    __syncthreads();
    float acc = b0[d];
    const float* w = W0 + d;
    const float* qr = sbuf + sub * 64;
    #pragma unroll 32
    for (int x = 0; x < XD; ++x) acc = fmaf(qr[x], w[x * DD], acc);
    qph[(size_t)row * DD + d] = (_Float16)acc;
  } else {
    // W1 B-fragments, fragment-ordered for coalesced register loads in main.
    // idx = (((wcol*4+kk)*4+jt)*64 + lane)*8 + e
    // value = W1[k][col], col = wcol*64 + jt*16 + (lane&15), k = kk*32 + (lane>>4)*8 + e
    #pragma unroll 8
    for (int i = 0; i < 64; ++i) {
      int idx = i * 256 + tid;
      int e = idx & 7;
      int lane = (idx >> 3) & 63;
      int jt = (idx >> 9) & 3;
      int kk = (idx >> 11) & 3;
      int wcol = (idx >> 13) & 1;
      int col = wcol * 64 + jt * 16 + (lane & 15);
      int k = kk * 32 + (lane >> 4) * 8 + e;
      w1f[idx] = (_Float16)W1[k * DD + col];
    }
  }
}

__launch_bounds__(256, 2)
__global__ void main_kernel(const float* __restrict__ logits,
                            const _Float16* __restrict__ fph,
                            const _Float16* __restrict__ qph,
                            const _Float16* __restrict__ w1f,
                            const float* __restrict__ b1,
                            const float* __restrict__ Wo,
                            const float* __restrict__ bo,
                            float* __restrict__ out) {
  __shared__ __align__(16) _Float16 h1[2][128 * 128];  // 2 x 32KB, XOR-swizzled f16
  __shared__ float att[CL];
  __shared__ float g[4][DD];
  __shared__ float red[8];
  __shared__ float part[8][YD];

  const int tid = threadIdx.x;
  const int bid = blockIdx.x;          // b*QL + qi
  const int wid = tid >> 6;
  const int ln  = tid & 63;
  const int b   = bid >> 7;
  const int wcol = wid & 1, wrow = wid >> 1;
  const int lhi = ln >> 4, llo = ln & 15;

  // ---- W1 B-fragments -> registers, once (coalesced dwordx4) ----
  f16x8 wf[4][4];
  {
    const uint4* ws = (const uint4*)w1f;
    #pragma unroll
    for (int kk = 0; kk < 4; ++kk)
      #pragma unroll
      for (int jt = 0; jt < 4; ++jt) {
        uint4 v = ws[(((wcol * 4 + kk) * 4 + jt) << 6) + ln];
        wf[kk][jt] = *(const f16x8*)&v;
      }
  }
  // ---- this lane's fixed 8-wide qp slice (d = (tid&15)*8 ..) ----
  uint4 qpv_u = ((const uint4*)(qph + (size_t)bid * DD))[tid & 15];
  const f16x8 qpv = *(const f16x8*)&qpv_u;

  ((float*)g)[tid] = 0.f;
  ((float*)g)[tid + 256] = 0.f;

  // ---- softmax over the 512 logits ----
  {
    const float* lg = logits + (size_t)bid * CL;
    float l0 = lg[tid], l1 = lg[tid + 256];
    float m = fmaxf(l0, l1);
    #pragma unroll
    for (int off = 1; off < 64; off <<= 1) m = fmaxf(m, __shfl_xor(m, off, 64));
    if (ln == 0) red[wid] = m;
    __syncthreads();
    m = fmaxf(fmaxf(red[0], red[1]), fmaxf(red[2], red[3]));
    float p0 = expf(l0 - m), p1 = expf(l1 - m);
    float s = p0 + p1;
    #pragma unroll
    for (int off = 1; off < 64; off <<= 1) s += __shfl_xor(s, off, 64);
    if (ln == 0) red[4 + wid] = s;
    __syncthreads();
    float inv = 1.f / (red[4] + red[5] + red[6] + red[7]);
    att[tid] = p0 * inv;
    att[tid + 256] = p1 * inv;
  }

  // ---- staging: thread owns rows i*16+(tid>>4), granule (tid&15) ----
  const int srow = tid >> 4;
  const int sg = tid & 15;
  const unsigned woff = (unsigned)(srow * 256 + ((sg * 16) ^ ((srow & 7) << 4)));

  uint4 sreg[8];
  auto stage_load = [&](int t) {
    const uint4* src = (const uint4*)(fph + ((size_t)b * CL + (size_t)t * 128) * DD);
    #pragma unroll
    for (int i = 0; i < 8; ++i) sreg[i] = src[i * 256 + tid];
  };
  auto stage_write = [&](int bufi) {
    char* base = (char*)&h1[bufi][0];
    const f16x8 zf = {};
    #pragma unroll
    for (int i = 0; i < 8; ++i) {
      f16x8 s = *(const f16x8*)&sreg[i] + qpv;     // v_pk_add_f16
      s = __builtin_elementwise_max(s, zf);        // v_pk_max_f16 (relu)
      *(f16x8*)(base + i * 4096 + woff) = s;       // ds_write_b128, swizzled
    }
  };

  stage_load(0);
  stage_write(0);

  const int swz = (llo & 7) << 4;
  const int c0 = wrow * 64 + llo;
  const int j0 = wcol * 64 + llo;
  float b1v[4];
  #pragma unroll
  for (int jt = 0; jt < 4; ++jt) b1v[jt] = b1[j0 + jt * 16];
  float gp[4] = {0.f, 0.f, 0.f, 0.f};

  __syncthreads();

  // ---- main loop: 4 c-tiles, double-buffered, ONE barrier per tile ----
  for (int t = 0; t < 4; ++t) {
    if (t < 3) stage_load(t + 1);                 // issue early (T14)

    const char* hb = (const char*)&h1[t & 1][0];
    f32x4 acc[4][4];
    #pragma unroll
    for (int ct = 0; ct < 4; ++ct)
      #pragma unroll
      for (int jt = 0; jt < 4; ++jt) acc[ct][jt] = (f32x4){0.f, 0.f, 0.f, 0.f};

    #pragma unroll
    for (int kk = 0; kk < 4; ++kk) {
      const int kb = (kk * 64 + lhi * 16) ^ swz;
      f16x8 a[4];
      #pragma unroll
      for (int ct = 0; ct < 4; ++ct)
        a[ct] = *(const f16x8*)(hb + (c0 + ct * 16) * 256 + kb);
      #pragma unroll
      for (int ct = 0; ct < 4; ++ct)
        #pragma unroll
        for (int jt = 0; jt < 4; ++jt)
          acc[ct][jt] = __builtin_amdgcn_mfma_f32_16x16x32_f16(a[ct], wf[kk][jt], acc[ct][jt], 0, 0, 0);
    }

    // epilogue: g[j] += att[c] * relu(H2 + b1)   (Wo GEMM commuted away)
    const int cbase = t * 128 + wrow * 64 + lhi * 4;
    #pragma unroll
    for (int ct = 0; ct < 4; ++ct) {
      #pragma unroll
      for (int r = 0; r < 4; ++r) {
        float wv = att[cbase + ct * 16 + r];
        #pragma unroll
        for (int jt = 0; jt < 4; ++jt) {
          float h = fmaxf(acc[ct][jt][r] + b1v[jt], 0.f);
          gp[jt] = fmaf(wv, h, gp[jt]);
        }
      }
    }

    if (t < 3) stage_write((t + 1) & 1);          // write late into other buffer
    __syncthreads();
  }

  // reduce gp across the 4 row-groups (cols identical across lhi)
  #pragma unroll
  for (int jt = 0; jt < 4; ++jt) {
    gp[jt] += __shfl_xor(gp[jt], 16, 64);
    gp[jt] += __shfl_xor(gp[jt], 32, 64);
  }
  if (ln < 16) {
    #pragma unroll
    for (int jt = 0; jt < 4; ++jt) g[wid][j0 + jt * 16] = gp[jt];
  }
  __syncthreads();

  // ---- y = g @ Wo + bo (fp32, tiny) ----
  {
    int y = tid & 31, ch = tid >> 5;
    float a = 0.f;
    #pragma unroll
    for (int jj = 0; jj < 16; ++jj) {
      int j = ch * 16 + jj;
      float gj = g[0][j] + g[1][j] + g[2][j] + g[3][j];
      a = fmaf(gj, Wo[j * YD + y], a);
    }
    part[ch][y] = a;
  }
  __syncthreads();
  if (tid < YD) {
    float a = bo[tid];
    #pragma unroll
    for (int ch = 0; ch < 8; ++ch) a += part[ch][tid];
    out[(size_t)bid * YD + tid] = a;
  }
}

extern "C" void kernel_launch(void* const* d_in, const int* in_sizes, int n_in,
                              void* d_out, int out_size, void* d_ws, size_t ws_size,
                              hipStream_t stream) {
  const float* q  = (const float*)d_in[0];
  const float* f  = (const float*)d_in[1];
  const float* lg = (const float*)d_in[2];
  const float* W0 = (const float*)d_in[3];
  const float* b0 = (const float*)d_in[4];
  const float* W1 = (const float*)d_in[5];
  const float* b1 = (const float*)d_in[6];
  const float* Wo = (const float*)d_in[7];
  const float* bo = (const float*)d_in[8];
  float* out = (float*)d_out;

  _Float16* fph = (_Float16*)d_ws;                       // 512 KB
  _Float16* qph = fph + (size_t)B_ * CL * DD;            // 128 KB
  _Float16* w1f = qph + (size_t)B_ * QL * DD;            //  32 KB

  prep_kernel<<<1281, 256, 0, stream>>>(q, f, W0, b0, W1, fph, qph, w1f);
  main_kernel<<<B_ * QL, 256, 0, stream>>>(lg, fph, qph, w1f, b1, Wo, bo, out);
}